// Round 1
// baseline (750.080 us; speedup 1.0000x reference)
//
#include <hip/hip_runtime.h>
#include <math.h>

// Problem constants (fixed by the reference): b=16, c=64, h=w=256, pool=8,
// wh=ww=32, n=64 windows, dim_k=64.
// out[b,c, nr*32+i, nc*32+j] = sum_m dist[b, nr*8+nc, m] * x[b,c, mr*32+i, mc*32+j]

// ---------------- Kernel 1: adaptive avg pool → y[b][n][c] ----------------
// One block per (b,c) plane (1024 blocks). Fully coalesced float4 reads.
__global__ __launch_bounds__(256) void pool_kernel(const float* __restrict__ x,
                                                   float* __restrict__ y)
{
    int bc = blockIdx.x;            // b*64 + c
    int b  = bc >> 6, c = bc & 63;
    const float4* plane = (const float4*)(x + (size_t)bc * 65536);
    int t    = threadIdx.x;
    int col4 = t & 63;              // float4 column within a row (0..63)
    int q    = t >> 6;              // wave id → row offset within 4-row slab
    __shared__ float red[256];

    for (int wr = 0; wr < 8; ++wr) {        // window-row
        float acc = 0.f;
#pragma unroll
        for (int it = 0; it < 8; ++it) {
            int row = wr * 32 + it * 4 + q;
            float4 v = plane[row * 64 + col4];
            acc += v.x + v.y + v.z + v.w;
        }
        red[t] = acc;
        __syncthreads();
        if (t < 8) {
            // window (wr, t): sum the 32 partials that belong to it
            float s = 0.f;
#pragma unroll
            for (int qq = 0; qq < 4; ++qq)
#pragma unroll
                for (int ss = 0; ss < 8; ++ss)
                    s += red[qq * 64 + t * 8 + ss];
            int n = wr * 8 + t;
            y[b * 4096 + n * 64 + c] = s * (1.0f / 1024.0f);
        }
        __syncthreads();
    }
}

// -------- Kernel 2: q,k,S,softmax → distT[b][m][n] (transposed!) ----------
// One block per batch (16 blocks). All tiny fp32 GEMMs from LDS.
__global__ __launch_bounds__(256) void attn_kernel(const float* __restrict__ y,
                                                   const float* __restrict__ Wq,
                                                   const float* __restrict__ Wk,
                                                   float* __restrict__ distT)
{
    __shared__ float yl[4096], wql[4096], wkl[4096], ql[4096], kl[4096];
    int b = blockIdx.x, t = threadIdx.x;
    for (int o = 0; o < 16; ++o) {
        yl [o * 256 + t] = y [b * 4096 + o * 256 + t];
        wql[o * 256 + t] = Wq[o * 256 + t];
        wkl[o * 256 + t] = Wk[o * 256 + t];
    }
    __syncthreads();

    // q[n][d] = y[n][:] . Wq[d][:]   (both rows contiguous)
#pragma unroll
    for (int o = 0; o < 16; ++o) {
        int idx = o * 256 + t, n = idx >> 6, d = idx & 63;
        const float4* yr = (const float4*)(yl + n * 64);
        const float4* aq = (const float4*)(wql + d * 64);
        const float4* ak = (const float4*)(wkl + d * 64);
        float sq = 0.f, sk = 0.f;
#pragma unroll
        for (int cc = 0; cc < 16; ++cc) {
            float4 a = yr[cc], u = aq[cc], v = ak[cc];
            sq += a.x * u.x + a.y * u.y + a.z * u.z + a.w * u.w;
            sk += a.x * v.x + a.y * v.y + a.z * v.z + a.w * v.w;
        }
        ql[idx] = sq; kl[idx] = sk;
    }
    __syncthreads();

    // S[n][m], softmax over m. 4 lanes per row n; lane handles 16 m's.
    int n = t >> 2, part = t & 3;
    float4 qreg[16];
    const float4* qr = (const float4*)(ql + n * 64);
#pragma unroll
    for (int cc = 0; cc < 16; ++cc) qreg[cc] = qr[cc];

    float s[16];
    const float scale = 0.125f;   // 1/sqrt(64)
#pragma unroll
    for (int mm = 0; mm < 16; ++mm) {
        int m = part * 16 + mm;
        const float4* kr = (const float4*)(kl + m * 64);
        float acc = 0.f;
#pragma unroll
        for (int cc = 0; cc < 16; ++cc) {
            float4 a = qreg[cc], v = kr[cc];
            acc += a.x * v.x + a.y * v.y + a.z * v.z + a.w * v.w;
        }
        s[mm] = acc * scale;
    }
    float mx = s[0];
#pragma unroll
    for (int mm = 1; mm < 16; ++mm) mx = fmaxf(mx, s[mm]);
    mx = fmaxf(mx, __shfl_xor(mx, 1));
    mx = fmaxf(mx, __shfl_xor(mx, 2));
    float sum = 0.f;
#pragma unroll
    for (int mm = 0; mm < 16; ++mm) { s[mm] = expf(s[mm] - mx); sum += s[mm]; }
    sum += __shfl_xor(sum, 1);
    sum += __shfl_xor(sum, 2);
    float inv = 1.0f / sum;
#pragma unroll
    for (int mm = 0; mm < 16; ++mm)
        distT[b * 4096 + (part * 16 + mm) * 64 + n] = s[mm] * inv;
}

// ------------- Kernel 3: out = dist-weighted window combine --------------
// Block = (b, c, ig): 4 local rows i = ig*4..+3 of every window.
// LDS: Xl = x rows needed (4 i × 8 m_row × 256 cols, padded), Dt = distT.
// Thread: j4 = t&7 (float4 col), i = (t>>3)&3, tg = t>>5 (= n_row);
// accumulates 8 windows (n = tg*8 + r) × 4 cols.
#define XL_ISTRIDE 2052   // 8*256 + 4 floats: breaks 4-way bank aliasing across i
__global__ __launch_bounds__(256) void combine_kernel(const float* __restrict__ x,
                                                      const float* __restrict__ distT,
                                                      float* __restrict__ out)
{
    __shared__ float Dt[4096];
    __shared__ float Xl[4 * XL_ISTRIDE];
    int blk = blockIdx.x;
    int ig  = blk & 7;          // i-group
    int bc  = blk >> 3;         // b*64 + c
    int b   = bc >> 6;
    const float* plane  = x   + (size_t)bc * 65536;
    float*       oplane = out + (size_t)bc * 65536;
    const float* dT     = distT + b * 4096;
    int t = threadIdx.x;

    // Load distT (coalesced, contiguous)
    for (int o = 0; o < 16; ++o) Dt[o * 256 + t] = dT[o * 256 + t];

    // Load x rows: row_local = i*8 + m_row → global row m_row*32 + ig*4 + i
    float4* Xl4 = (float4*)Xl;
    const float4* plane4 = (const float4*)plane;
#pragma unroll
    for (int o = 0; o < 8; ++o) {
        int f4        = o * 256 + t;
        int row_local = f4 >> 6;
        int col4      = f4 & 63;
        int i         = row_local >> 3;
        int m_row     = row_local & 7;
        int g_row     = m_row * 32 + ig * 4 + i;
        Xl4[i * (XL_ISTRIDE / 4) + m_row * 64 + col4] = plane4[g_row * 64 + col4];
    }
    __syncthreads();

    int j4 = t & 7;
    int i  = (t >> 3) & 3;
    int tg = t >> 5;            // n_row
    const float4* Xr = (const float4*)Xl + i * (XL_ISTRIDE / 4) + j4;
    const float4* Dr = (const float4*)Dt + tg * 2;

    float4 acc[8];
#pragma unroll
    for (int r = 0; r < 8; ++r) acc[r] = make_float4(0.f, 0.f, 0.f, 0.f);

#pragma unroll 8
    for (int m = 0; m < 64; ++m) {
        int m_row = m >> 3, m_col = m & 7;
        float4 v  = Xr[m_row * 64 + m_col * 8];
        float4 d0 = Dr[m * 16];
        float4 d1 = Dr[m * 16 + 1];
        acc[0].x += d0.x * v.x; acc[0].y += d0.x * v.y; acc[0].z += d0.x * v.z; acc[0].w += d0.x * v.w;
        acc[1].x += d0.y * v.x; acc[1].y += d0.y * v.y; acc[1].z += d0.y * v.z; acc[1].w += d0.y * v.w;
        acc[2].x += d0.z * v.x; acc[2].y += d0.z * v.y; acc[2].z += d0.z * v.z; acc[2].w += d0.z * v.w;
        acc[3].x += d0.w * v.x; acc[3].y += d0.w * v.y; acc[3].z += d0.w * v.z; acc[3].w += d0.w * v.w;
        acc[4].x += d1.x * v.x; acc[4].y += d1.x * v.y; acc[4].z += d1.x * v.z; acc[4].w += d1.x * v.w;
        acc[5].x += d1.y * v.x; acc[5].y += d1.y * v.y; acc[5].z += d1.y * v.z; acc[5].w += d1.y * v.w;
        acc[6].x += d1.z * v.x; acc[6].y += d1.z * v.y; acc[6].z += d1.z * v.z; acc[6].w += d1.z * v.w;
        acc[7].x += d1.w * v.x; acc[7].y += d1.w * v.y; acc[7].z += d1.w * v.z; acc[7].w += d1.w * v.w;
    }

    // Write: row = tg*32 + ig*4 + i (one row per thread), cols r*32 + j4*4
    float4* orow = (float4*)(oplane + (tg * 32 + ig * 4 + i) * 256) + j4;
#pragma unroll
    for (int r = 0; r < 8; ++r) orow[r * 8] = acc[r];
}

extern "C" void kernel_launch(void* const* d_in, const int* in_sizes, int n_in,
                              void* d_out, int out_size, void* d_ws, size_t ws_size,
                              hipStream_t stream)
{
    const float* x  = (const float*)d_in[0];   // (16, 64, 256, 256)
    const float* Wq = (const float*)d_in[1];   // (64, 64)
    const float* Wk = (const float*)d_in[2];   // (64, 64)
    float* out = (float*)d_out;                // (16, 64, 256, 256)

    float* y_ws  = (float*)d_ws;               // 65536 floats: y[b][n][c]
    float* distT = y_ws + 65536;               // 65536 floats: distT[b][m][n]

    pool_kernel   <<<1024, 256, 0, stream>>>(x, y_ws);
    attn_kernel   <<<16,   256, 0, stream>>>(y_ws, Wq, Wk, distT);
    combine_kernel<<<8192, 256, 0, stream>>>(x, distT, out);
}

// Round 2
// 525.218 us; speedup vs baseline: 1.4281x; 1.4281x over previous
//
#include <hip/hip_runtime.h>
#include <math.h>

// Problem constants: b=16, c=64, h=w=256, pool=8, wh=ww=32, n=64, dim_k=64.
// out[b,c, nr*32+i, nc*32+j] = sum_m dist[b, nr*8+nc, m] * x[b,c, mr*32+i, mc*32+j]

// ---------------- Kernel 1: adaptive avg pool → yT[b][c][n] ----------------
// One block per (b,c) plane (1024 blocks). Fully coalesced float4 reads.
__global__ __launch_bounds__(256) void pool_kernel(const float* __restrict__ x,
                                                   float* __restrict__ yT)
{
    int bc = blockIdx.x;            // b*64 + c
    int b  = bc >> 6, c = bc & 63;
    const float4* plane = (const float4*)(x + (size_t)bc * 65536);
    int t    = threadIdx.x;
    int col4 = t & 63;              // float4 column within a row (0..63)
    int q    = t >> 6;              // wave id → row offset within 4-row slab
    __shared__ float red[256];

    for (int wr = 0; wr < 8; ++wr) {        // window-row
        float acc = 0.f;
#pragma unroll
        for (int it = 0; it < 8; ++it) {
            int row = wr * 32 + it * 4 + q;
            float4 v = plane[row * 64 + col4];
            acc += v.x + v.y + v.z + v.w;
        }
        red[t] = acc;
        __syncthreads();
        if (t < 8) {
            float s = 0.f;
#pragma unroll
            for (int qq = 0; qq < 4; ++qq)
#pragma unroll
                for (int ss = 0; ss < 8; ++ss)
                    s += red[qq * 64 + t * 8 + ss];
            int n = wr * 8 + t;
            yT[b * 4096 + c * 64 + n] = s * (1.0f / 1024.0f);
        }
        __syncthreads();
    }
}

// -------- Kernel 2: q,k,S,softmax → distT[b][m][n] (transposed) ----------
// One block per batch. ALL LDS accesses are unit-stride across lanes or
// wave-uniform broadcast. ng = t>>6 is wave-uniform; lane = t&63.
#define ST 68   // padded stride: float4-aligned, breaks power-of-2 banking
__global__ __launch_bounds__(256) void attn_kernel(const float* __restrict__ yT,
                                                   const float* __restrict__ Wq,
                                                   const float* __restrict__ Wk,
                                                   float* __restrict__ distT)
{
    __shared__ float ylT[64 * ST];  // [c][n]
    __shared__ float wqT[64 * ST];  // [c][d]
    __shared__ float wkT[64 * ST];  // [c][d]
    __shared__ float qlT[64 * ST];  // [d][n]
    __shared__ float klT[64 * ST];  // [d][m]
    __shared__ float sT [64 * ST];  // [m][n]
    int b = blockIdx.x, t = threadIdx.x;

    // Load: yT rows copy straight in (lanes consecutive); W transposed
    // (write banks (4c+d)%32: <=8-way, one-time cost, negligible).
#pragma unroll
    for (int o = 0; o < 16; ++o) {
        int idx = o * 256 + t;
        int r = idx >> 6, cl = idx & 63;    // r wave-uniform, cl = lane
        ylT[r * ST + cl] = yT[b * 4096 + idx];
        wqT[cl * ST + r] = Wq[idx];
        wkT[cl * ST + r] = Wk[idx];
    }
    __syncthreads();

    int lane = t & 63, ng = t >> 6;   // ng wave-uniform

    // Phase 2: q[n][d], k[n][d] for d=lane, n = ng*16..+15
    float qa[16], ka[16];
#pragma unroll
    for (int i = 0; i < 16; ++i) { qa[i] = 0.f; ka[i] = 0.f; }
    for (int c = 0; c < 64; ++c) {
        float wq = wqT[c * ST + lane];          // unit-stride across lanes
        float wk = wkT[c * ST + lane];
        const float4* yr = (const float4*)(ylT + c * ST + ng * 16);  // broadcast
        float4 y0 = yr[0], y1 = yr[1], y2 = yr[2], y3 = yr[3];
        qa[0]  += y0.x * wq; qa[1]  += y0.y * wq; qa[2]  += y0.z * wq; qa[3]  += y0.w * wq;
        qa[4]  += y1.x * wq; qa[5]  += y1.y * wq; qa[6]  += y1.z * wq; qa[7]  += y1.w * wq;
        qa[8]  += y2.x * wq; qa[9]  += y2.y * wq; qa[10] += y2.z * wq; qa[11] += y2.w * wq;
        qa[12] += y3.x * wq; qa[13] += y3.y * wq; qa[14] += y3.z * wq; qa[15] += y3.w * wq;
        ka[0]  += y0.x * wk; ka[1]  += y0.y * wk; ka[2]  += y0.z * wk; ka[3]  += y0.w * wk;
        ka[4]  += y1.x * wk; ka[5]  += y1.y * wk; ka[6]  += y1.z * wk; ka[7]  += y1.w * wk;
        ka[8]  += y2.x * wk; ka[9]  += y2.y * wk; ka[10] += y2.z * wk; ka[11] += y2.w * wk;
        ka[12] += y3.x * wk; ka[13] += y3.y * wk; ka[14] += y3.z * wk; ka[15] += y3.w * wk;
    }
    // Store transposed: qlT[d][n], klT[d][m]
    {
        float4* qd = (float4*)(qlT + lane * ST + ng * 16);
        float4* kd = (float4*)(klT + lane * ST + ng * 16);
        qd[0] = make_float4(qa[0],  qa[1],  qa[2],  qa[3]);
        qd[1] = make_float4(qa[4],  qa[5],  qa[6],  qa[7]);
        qd[2] = make_float4(qa[8],  qa[9],  qa[10], qa[11]);
        qd[3] = make_float4(qa[12], qa[13], qa[14], qa[15]);
        kd[0] = make_float4(ka[0],  ka[1],  ka[2],  ka[3]);
        kd[1] = make_float4(ka[4],  ka[5],  ka[6],  ka[7]);
        kd[2] = make_float4(ka[8],  ka[9],  ka[10], ka[11]);
        kd[3] = make_float4(ka[12], ka[13], ka[14], ka[15]);
    }
    __syncthreads();

    // Phase 3: S[n][m] for m=lane, n = ng*16..+15
    float s[16];
#pragma unroll
    for (int i = 0; i < 16; ++i) s[i] = 0.f;
    for (int d = 0; d < 64; ++d) {
        float kv = klT[d * ST + lane];          // unit-stride
        const float4* qr = (const float4*)(qlT + d * ST + ng * 16);  // broadcast
        float4 q0 = qr[0], q1 = qr[1], q2 = qr[2], q3 = qr[3];
        s[0]  += q0.x * kv; s[1]  += q0.y * kv; s[2]  += q0.z * kv; s[3]  += q0.w * kv;
        s[4]  += q1.x * kv; s[5]  += q1.y * kv; s[6]  += q1.z * kv; s[7]  += q1.w * kv;
        s[8]  += q2.x * kv; s[9]  += q2.y * kv; s[10] += q2.z * kv; s[11] += q2.w * kv;
        s[12] += q3.x * kv; s[13] += q3.y * kv; s[14] += q3.z * kv; s[15] += q3.w * kv;
    }
    const float scale = 0.125f;   // 1/sqrt(64)
#pragma unroll
    for (int i = 0; i < 16; ++i) {
        float v = s[i] * scale;
        float mx = v;
        mx = fmaxf(mx, __shfl_xor(mx, 1));
        mx = fmaxf(mx, __shfl_xor(mx, 2));
        mx = fmaxf(mx, __shfl_xor(mx, 4));
        mx = fmaxf(mx, __shfl_xor(mx, 8));
        mx = fmaxf(mx, __shfl_xor(mx, 16));
        mx = fmaxf(mx, __shfl_xor(mx, 32));
        float e = expf(v - mx);
        float sm = e;
        sm += __shfl_xor(sm, 1);
        sm += __shfl_xor(sm, 2);
        sm += __shfl_xor(sm, 4);
        sm += __shfl_xor(sm, 8);
        sm += __shfl_xor(sm, 16);
        sm += __shfl_xor(sm, 32);
        s[i] = e / sm;            // dist[n = ng*16+i][m = lane]
    }
    // Stage transposed into sT[m][n]
    {
        float4* sd = (float4*)(sT + lane * ST + ng * 16);
        sd[0] = make_float4(s[0],  s[1],  s[2],  s[3]);
        sd[1] = make_float4(s[4],  s[5],  s[6],  s[7]);
        sd[2] = make_float4(s[8],  s[9],  s[10], s[11]);
        sd[3] = make_float4(s[12], s[13], s[14], s[15]);
    }
    __syncthreads();

    // Coalesced global write of distT[b][m][n]
#pragma unroll
    for (int o = 0; o < 16; ++o) {
        int idx = o * 256 + t;
        int m = idx >> 6, n = idx & 63;         // m wave-uniform, n = lane
        distT[b * 4096 + idx] = sT[m * ST + n];
    }
}

// ------------- Kernel 3: out = dist-weighted window combine --------------
// (unchanged this round — want clean counters for it next round)
#define XL_ISTRIDE 2052   // 8*256 + 4 floats
__global__ __launch_bounds__(256) void combine_kernel(const float* __restrict__ x,
                                                      const float* __restrict__ distT,
                                                      float* __restrict__ out)
{
    __shared__ float Dt[4096];
    __shared__ float Xl[4 * XL_ISTRIDE];
    int blk = blockIdx.x;
    int ig  = blk & 7;          // i-group
    int bc  = blk >> 3;         // b*64 + c
    int b   = bc >> 6;
    const float* plane  = x   + (size_t)bc * 65536;
    float*       oplane = out + (size_t)bc * 65536;
    const float* dT     = distT + b * 4096;
    int t = threadIdx.x;

    for (int o = 0; o < 16; ++o) Dt[o * 256 + t] = dT[o * 256 + t];

    float4* Xl4 = (float4*)Xl;
    const float4* plane4 = (const float4*)plane;
#pragma unroll
    for (int o = 0; o < 8; ++o) {
        int f4        = o * 256 + t;
        int row_local = f4 >> 6;
        int col4      = f4 & 63;
        int i         = row_local >> 3;
        int m_row     = row_local & 7;
        int g_row     = m_row * 32 + ig * 4 + i;
        Xl4[i * (XL_ISTRIDE / 4) + m_row * 64 + col4] = plane4[g_row * 64 + col4];
    }
    __syncthreads();

    int j4 = t & 7;
    int i  = (t >> 3) & 3;
    int tg = t >> 5;            // n_row
    const float4* Xr = (const float4*)Xl + i * (XL_ISTRIDE / 4) + j4;
    const float4* Dr = (const float4*)Dt + tg * 2;

    float4 acc[8];
#pragma unroll
    for (int r = 0; r < 8; ++r) acc[r] = make_float4(0.f, 0.f, 0.f, 0.f);

#pragma unroll 8
    for (int m = 0; m < 64; ++m) {
        int m_row = m >> 3, m_col = m & 7;
        float4 v  = Xr[m_row * 64 + m_col * 8];
        float4 d0 = Dr[m * 16];
        float4 d1 = Dr[m * 16 + 1];
        acc[0].x += d0.x * v.x; acc[0].y += d0.x * v.y; acc[0].z += d0.x * v.z; acc[0].w += d0.x * v.w;
        acc[1].x += d0.y * v.x; acc[1].y += d0.y * v.y; acc[1].z += d0.y * v.z; acc[1].w += d0.y * v.w;
        acc[2].x += d0.z * v.x; acc[2].y += d0.z * v.y; acc[2].z += d0.z * v.z; acc[2].w += d0.z * v.w;
        acc[3].x += d0.w * v.x; acc[3].y += d0.w * v.y; acc[3].z += d0.w * v.z; acc[3].w += d0.w * v.w;
        acc[4].x += d1.x * v.x; acc[4].y += d1.x * v.y; acc[4].z += d1.x * v.z; acc[4].w += d1.x * v.w;
        acc[5].x += d1.y * v.x; acc[5].y += d1.y * v.y; acc[5].z += d1.y * v.z; acc[5].w += d1.y * v.w;
        acc[6].x += d1.z * v.x; acc[6].y += d1.z * v.y; acc[6].z += d1.z * v.z; acc[6].w += d1.z * v.w;
        acc[7].x += d1.w * v.x; acc[7].y += d1.w * v.y; acc[7].z += d1.w * v.z; acc[7].w += d1.w * v.w;
    }

    float4* orow = (float4*)(oplane + (tg * 32 + ig * 4 + i) * 256) + j4;
#pragma unroll
    for (int r = 0; r < 8; ++r) orow[r * 8] = acc[r];
}

extern "C" void kernel_launch(void* const* d_in, const int* in_sizes, int n_in,
                              void* d_out, int out_size, void* d_ws, size_t ws_size,
                              hipStream_t stream)
{
    const float* x  = (const float*)d_in[0];   // (16, 64, 256, 256)
    const float* Wq = (const float*)d_in[1];   // (64, 64)
    const float* Wk = (const float*)d_in[2];   // (64, 64)
    float* out = (float*)d_out;                // (16, 64, 256, 256)

    float* y_ws  = (float*)d_ws;               // 65536 floats: yT[b][c][n]
    float* distT = y_ws + 65536;               // 65536 floats: distT[b][m][n]

    pool_kernel   <<<1024, 256, 0, stream>>>(x, y_ws);
    attn_kernel   <<<16,   256, 0, stream>>>(y_ws, Wq, Wk, distT);
    combine_kernel<<<8192, 256, 0, stream>>>(x, distT, out);
}